// Round 1
// baseline (743.713 us; speedup 1.0000x reference)
//
#include <hip/hip_runtime.h>
#include <hip/hip_bf16.h>

#define NUM_CLASSES 100000
#define NUM_SAMPLED 5000
#define BATCH 4096
#define DIM 1024
#define NPAD 5120   // 5000 padded to 40 tiles of 128

typedef float floatx4 __attribute__((ext_vector_type(4)));
typedef short bf16x8 __attribute__((ext_vector_type(8)));

// ---------------------------------------------------------------- helpers
__device__ __forceinline__ float log_expected_count(int c) {
    // p = log((c+2)/(c+1)) / log(NUM_CLASSES+1)
    float p = log1pf(1.0f / (float)(c + 1)) / logf((float)NUM_CLASSES + 1.0f);
    float t = (float)NUM_SAMPLED * log1pf(-p);
    return logf(-expm1f(t));
}

__device__ __forceinline__ void async_ld16(const void* g, void* l) {
    __builtin_amdgcn_global_load_lds(
        (const __attribute__((address_space(1))) unsigned int*)g,
        (__attribute__((address_space(3))) unsigned int*)l,
        16, 0, 0);
}

// ---------------------------------------------------------------- init
__global__ __launch_bounds__(256) void init_kernel(float* rowsum, float* out) {
    int i = blockIdx.x * 256 + threadIdx.x;
    if (i < BATCH) rowsum[i] = 0.0f;
    if (i == 0) out[0] = 0.0f;
}

// ---------------------------------------------------------------- x -> bf16
__global__ __launch_bounds__(256) void convert_x_kernel(const float* __restrict__ x,
                                                        __hip_bfloat16* __restrict__ A) {
    int i = (blockIdx.x * 256 + threadIdx.x) * 4;
    float4 v = *reinterpret_cast<const float4*>(x + i);
    union { ushort4 u; __hip_bfloat16 h[4]; } o;
    o.h[0] = __float2bfloat16(v.x);
    o.h[1] = __float2bfloat16(v.y);
    o.h[2] = __float2bfloat16(v.z);
    o.h[3] = __float2bfloat16(v.w);
    *reinterpret_cast<ushort4*>(A + i) = o.u;
}

// ---------------------------------------------------------------- gather w[:,sampled] -> BT[n][k] bf16 (n-major, k contiguous)
// also computes shift[n] = b[c] - logE(c)  (or -1e30 for padding)
__global__ __launch_bounds__(256) void gather_b_kernel(const float* __restrict__ w,
                                                       const float* __restrict__ b,
                                                       const int* __restrict__ sampled,
                                                       __hip_bfloat16* __restrict__ BT,
                                                       float* __restrict__ shift) {
    int n  = blockIdx.x * 256 + threadIdx.x;   // [0, 5120)
    int k0 = blockIdx.y * 64;                  // 16 chunks of 64 k
    bool valid = (n < NUM_SAMPLED);
    int c = valid ? sampled[n] : 0;
    if (blockIdx.y == 0) {
        shift[n] = valid ? (b[c] - log_expected_count(c)) : -1e30f;
    }
    __hip_bfloat16* dst = BT + (size_t)n * DIM + k0;
    if (valid) {
        const float* src = w + (size_t)k0 * NUM_CLASSES + c;
        for (int kk = 0; kk < 64; kk += 8) {
            union { uint4 u; __hip_bfloat16 h[8]; } o;
            #pragma unroll
            for (int j = 0; j < 8; j++)
                o.h[j] = __float2bfloat16(src[(size_t)(kk + j) * NUM_CLASSES]);
            *reinterpret_cast<uint4*>(dst + kk) = o.u;
        }
    } else {
        uint4 z; z.x = z.y = z.z = z.w = 0u;
        for (int kk = 0; kk < 64; kk += 8)
            *reinterpret_cast<uint4*>(dst + kk) = z;
    }
}

// ---------------------------------------------------------------- GEMM 4096x5120x1024 bf16 + fused exp-rowsum epilogue
// A: [M][K] bf16 row-major.  BT: [N][K] bf16 row-major.  acc = A·B.
// Epilogue: rowsum[m] += sum_n exp(acc[m][n] + shift[n])
#define BM 128
#define BN 128
#define BK 64

__global__ __launch_bounds__(256) void gemm_kernel(const __hip_bfloat16* __restrict__ A,
                                                   const __hip_bfloat16* __restrict__ BT,
                                                   const float* __restrict__ shift,
                                                   float* __restrict__ rowsum) {
    __shared__ __hip_bfloat16 As[BM * BK];   // 16 KB
    __shared__ __hip_bfloat16 Bs[BN * BK];   // 16 KB

    const int tid  = threadIdx.x;
    const int m0   = blockIdx.x * BM;   // 32 m-tiles
    const int n0   = blockIdx.y * BN;   // 40 n-tiles
    const int lane = tid & 63;
    const int wv   = tid >> 6;          // wave 0..3
    const int wm   = (wv >> 1) * 64;    // 2x2 wave layout of 64x64 quadrants
    const int wn   = (wv & 1) * 64;
    const int col  = lane & 15;
    const int quad = lane >> 4;

    floatx4 acc[4][4] = {};

    // staging: thread stages 16B at LDS byte offset tid*16 + r*4096, r=0..3
    // (wave-uniform base + lane*16 as required by global_load_lds)
    const __hip_bfloat16* gA[4];
    const __hip_bfloat16* gB[4];
    int ldsOff[4];
    #pragma unroll
    for (int r = 0; r < 4; r++) {
        int eo  = tid * 8 + r * 2048;     // element offset in [128][64] tile
        int row = eo >> 6;
        int cl  = eo & 63;
        gA[r] = A  + (size_t)(m0 + row) * DIM + cl;
        gB[r] = BT + (size_t)(n0 + row) * DIM + cl;
        ldsOff[r] = eo;
    }

    for (int kt = 0; kt < DIM; kt += BK) {
        #pragma unroll
        for (int r = 0; r < 4; r++)
            async_ld16(gA[r] + kt, &As[ldsOff[r]]);
        #pragma unroll
        for (int r = 0; r < 4; r++)
            async_ld16(gB[r] + kt, &Bs[ldsOff[r]]);
        __syncthreads();   // drains vmcnt before LDS reads

        #pragma unroll
        for (int ks = 0; ks < 2; ks++) {
            const int kc = ks * 32 + quad * 8;
            bf16x8 af[4], bfr[4];
            #pragma unroll
            for (int i = 0; i < 4; i++) {
                af[i]  = *reinterpret_cast<const bf16x8*>(&As[(wm + i * 16 + col) * BK + kc]);
                bfr[i] = *reinterpret_cast<const bf16x8*>(&Bs[(wn + i * 16 + col) * BK + kc]);
            }
            #pragma unroll
            for (int i = 0; i < 4; i++)
                #pragma unroll
                for (int j = 0; j < 4; j++)
                    acc[i][j] = __builtin_amdgcn_mfma_f32_16x16x32_bf16(af[i], bfr[j], acc[i][j], 0, 0, 0);
        }
        __syncthreads();
    }

    // ---- fused epilogue: per-row sum of exp(logit + shift[n])
    // C/D layout: col = lane&15 (n), row = quad*4 + reg (m)
    float sh[4];
    #pragma unroll
    for (int j = 0; j < 4; j++)
        sh[j] = shift[n0 + wn + j * 16 + col];

    #pragma unroll
    for (int i = 0; i < 4; i++) {
        #pragma unroll
        for (int r = 0; r < 4; r++) {
            float s = 0.0f;
            #pragma unroll
            for (int j = 0; j < 4; j++)
                s += __expf(acc[i][j][r] + sh[j]);
            // reduce across the 16 n-lanes (lane bits 0..3) — rows identical there
            s += __shfl_xor(s, 1);
            s += __shfl_xor(s, 2);
            s += __shfl_xor(s, 4);
            s += __shfl_xor(s, 8);
            if (col == 0) {
                int mrow = m0 + wm + i * 16 + quad * 4 + r;
                atomicAdd(&rowsum[mrow], s);
            }
        }
    }
}

// ---------------------------------------------------------------- true logits + final loss
__global__ __launch_bounds__(256) void loss_kernel(const float* __restrict__ x,
                                                   const float* __restrict__ w,
                                                   const float* __restrict__ b,
                                                   const int* __restrict__ labels,
                                                   const float* __restrict__ rowsum,
                                                   float* __restrict__ out) {
    __shared__ float red[4];
    const int m = blockIdx.x;
    const int t = threadIdx.x;
    const int lbl = labels[m];
    const float* xr = x + (size_t)m * DIM;
    const float* wc = w + lbl;

    float p = 0.0f;
    #pragma unroll
    for (int d = t; d < DIM; d += 256)
        p += xr[d] * wc[(size_t)d * NUM_CLASSES];

    #pragma unroll
    for (int off = 32; off > 0; off >>= 1)
        p += __shfl_xor(p, off);
    if ((t & 63) == 0) red[t >> 6] = p;
    __syncthreads();
    if (t == 0) {
        float tl = red[0] + red[1] + red[2] + red[3] + b[lbl] - log_expected_count(lbl);
        float total = rowsum[m] + __expf(tl);
        atomicAdd(out, (logf(total) - tl) * (1.0f / (float)BATCH));
    }
}

// ---------------------------------------------------------------- launch
extern "C" void kernel_launch(void* const* d_in, const int* in_sizes, int n_in,
                              void* d_out, int out_size, void* d_ws, size_t ws_size,
                              hipStream_t stream) {
    const float* x       = (const float*)d_in[0];
    const float* w       = (const float*)d_in[1];
    const float* b       = (const float*)d_in[2];
    const int*   labels  = (const int*)d_in[3];
    const int*   sampled = (const int*)d_in[4];
    float* out = (float*)d_out;

    char* ws = (char*)d_ws;
    __hip_bfloat16* A  = (__hip_bfloat16*)(ws);                       // 8 MB
    __hip_bfloat16* BT = (__hip_bfloat16*)(ws + (size_t)8  * 1024 * 1024); // 10 MB
    float* shift  = (float*)(ws + (size_t)18 * 1024 * 1024);          // 20 KB
    float* rowsum = (float*)(ws + (size_t)18 * 1024 * 1024 + 64 * 1024);  // 16 KB

    hipLaunchKernelGGL(init_kernel, dim3(16), dim3(256), 0, stream, rowsum, out);
    hipLaunchKernelGGL(convert_x_kernel, dim3((BATCH * DIM / 4) / 256), dim3(256), 0, stream, x, A);
    hipLaunchKernelGGL(gather_b_kernel, dim3(NPAD / 256, DIM / 64), dim3(256), 0, stream,
                       w, b, sampled, BT, shift);
    hipLaunchKernelGGL(gemm_kernel, dim3(BATCH / BM, NPAD / BN), dim3(256), 0, stream,
                       A, BT, shift, rowsum);
    hipLaunchKernelGGL(loss_kernel, dim3(BATCH), dim3(256), 0, stream,
                       x, w, b, labels, rowsum, out);
}

// Round 2
// 720.379 us; speedup vs baseline: 1.0324x; 1.0324x over previous
//
#include <hip/hip_runtime.h>
#include <hip/hip_bf16.h>

#define NUM_CLASSES 100000
#define NUM_SAMPLED 5000
#define BATCH 4096
#define DIM 1024
#define NPAD 5120   // 5000 padded to 40 tiles of 128

typedef float floatx4 __attribute__((ext_vector_type(4)));
typedef short bf16x8 __attribute__((ext_vector_type(8)));

// ---------------------------------------------------------------- helpers
__device__ __forceinline__ float log_expected_count(int c) {
    // p = log((c+2)/(c+1)) / log(NUM_CLASSES+1)
    float p = log1pf(1.0f / (float)(c + 1)) / logf((float)NUM_CLASSES + 1.0f);
    float t = (float)NUM_SAMPLED * log1pf(-p);
    return logf(-expm1f(t));
}

__device__ __forceinline__ void async_ld16(const void* g, void* l) {
    __builtin_amdgcn_global_load_lds(
        (const __attribute__((address_space(1))) unsigned int*)g,
        (__attribute__((address_space(3))) unsigned int*)l,
        16, 0, 0);
}

// ---------------------------------------------------------------- init
__global__ __launch_bounds__(256) void init_kernel(float* rowsum) {
    int i = blockIdx.x * 256 + threadIdx.x;
    if (i < BATCH) rowsum[i] = 0.0f;
}

// ---------------------------------------------------------------- x -> bf16
__global__ __launch_bounds__(256) void convert_x_kernel(const float* __restrict__ x,
                                                        __hip_bfloat16* __restrict__ A) {
    int i = (blockIdx.x * 256 + threadIdx.x) * 4;
    float4 v = *reinterpret_cast<const float4*>(x + i);
    union { ushort4 u; __hip_bfloat16 h[4]; } o;
    o.h[0] = __float2bfloat16(v.x);
    o.h[1] = __float2bfloat16(v.y);
    o.h[2] = __float2bfloat16(v.z);
    o.h[3] = __float2bfloat16(v.w);
    *reinterpret_cast<ushort4*>(A + i) = o.u;
}

// ---------------------------------------------------------------- gather w[:,sampled] -> BT[n][k] bf16 (n-major, k contiguous)
// also computes shift[n] = b[c] - logE(c)  (or -1e30 for padding)
// grid: (NPAD/256, DIM/16) — 1280 blocks for memory-level parallelism
__global__ __launch_bounds__(256) void gather_b_kernel(const float* __restrict__ w,
                                                       const float* __restrict__ b,
                                                       const int* __restrict__ sampled,
                                                       __hip_bfloat16* __restrict__ BT,
                                                       float* __restrict__ shift) {
    int n  = blockIdx.x * 256 + threadIdx.x;   // [0, 5120)
    int k0 = blockIdx.y * 16;                  // 64 chunks of 16 k
    bool valid = (n < NUM_SAMPLED);
    int c = valid ? sampled[n] : 0;
    if (blockIdx.y == 0) {
        shift[n] = valid ? (b[c] - log_expected_count(c)) : -1e30f;
    }
    __hip_bfloat16* dst = BT + (size_t)n * DIM + k0;
    if (valid) {
        const float* src = w + (size_t)k0 * NUM_CLASSES + c;
        #pragma unroll
        for (int kk = 0; kk < 16; kk += 8) {
            union { uint4 u; __hip_bfloat16 h[8]; } o;
            #pragma unroll
            for (int j = 0; j < 8; j++)
                o.h[j] = __float2bfloat16(src[(size_t)(kk + j) * NUM_CLASSES]);
            *reinterpret_cast<uint4*>(dst + kk) = o.u;
        }
    } else {
        uint4 z; z.x = z.y = z.z = z.w = 0u;
        #pragma unroll
        for (int kk = 0; kk < 16; kk += 8)
            *reinterpret_cast<uint4*>(dst + kk) = z;
    }
}

// ---------------------------------------------------------------- GEMM 4096x5120x1024 bf16 + fused exp-rowsum epilogue
// A: [M][K] bf16 row-major.  BT: [N][K] bf16 row-major.  acc = A·B.
// Epilogue: rowsum[m] += sum_n exp(acc[m][n] + shift[n])
#define BM 128
#define BN 128
#define BK 64

__global__ __launch_bounds__(256) void gemm_kernel(const __hip_bfloat16* __restrict__ A,
                                                   const __hip_bfloat16* __restrict__ BT,
                                                   const float* __restrict__ shift,
                                                   float* __restrict__ rowsum) {
    __shared__ __hip_bfloat16 As[BM * BK];   // 16 KB
    __shared__ __hip_bfloat16 Bs[BN * BK];   // 16 KB

    const int tid  = threadIdx.x;
    const int m0   = blockIdx.x * BM;   // 32 m-tiles
    const int n0   = blockIdx.y * BN;   // 40 n-tiles
    const int lane = tid & 63;
    const int wv   = tid >> 6;          // wave 0..3
    const int wm   = (wv >> 1) * 64;    // 2x2 wave layout of 64x64 quadrants
    const int wn   = (wv & 1) * 64;
    const int col  = lane & 15;
    const int quad = lane >> 4;

    floatx4 acc[4][4] = {};

    // staging: thread stages 16B at LDS byte offset tid*16 + r*4096, r=0..3
    // (wave-uniform base + lane*16 as required by global_load_lds)
    const __hip_bfloat16* gA[4];
    const __hip_bfloat16* gB[4];
    int ldsOff[4];
    #pragma unroll
    for (int r = 0; r < 4; r++) {
        int eo  = tid * 8 + r * 2048;     // element offset in [128][64] tile
        int row = eo >> 6;
        int cl  = eo & 63;
        gA[r] = A  + (size_t)(m0 + row) * DIM + cl;
        gB[r] = BT + (size_t)(n0 + row) * DIM + cl;
        ldsOff[r] = eo;
    }

    for (int kt = 0; kt < DIM; kt += BK) {
        #pragma unroll
        for (int r = 0; r < 4; r++)
            async_ld16(gA[r] + kt, &As[ldsOff[r]]);
        #pragma unroll
        for (int r = 0; r < 4; r++)
            async_ld16(gB[r] + kt, &Bs[ldsOff[r]]);
        __syncthreads();   // drains vmcnt before LDS reads

        #pragma unroll
        for (int ks = 0; ks < 2; ks++) {
            const int kc = ks * 32 + quad * 8;
            bf16x8 af[4], bfr[4];
            #pragma unroll
            for (int i = 0; i < 4; i++) {
                af[i]  = *reinterpret_cast<const bf16x8*>(&As[(wm + i * 16 + col) * BK + kc]);
                bfr[i] = *reinterpret_cast<const bf16x8*>(&Bs[(wn + i * 16 + col) * BK + kc]);
            }
            #pragma unroll
            for (int i = 0; i < 4; i++)
                #pragma unroll
                for (int j = 0; j < 4; j++)
                    acc[i][j] = __builtin_amdgcn_mfma_f32_16x16x32_bf16(af[i], bfr[j], acc[i][j], 0, 0, 0);
        }
        __syncthreads();
    }

    // ---- fused epilogue: per-row sum of exp(logit + shift[n])
    // C/D layout: col = lane&15 (n), row = quad*4 + reg (m)
    float sh[4];
    #pragma unroll
    for (int j = 0; j < 4; j++)
        sh[j] = shift[n0 + wn + j * 16 + col];

    #pragma unroll
    for (int i = 0; i < 4; i++) {
        #pragma unroll
        for (int r = 0; r < 4; r++) {
            float s = 0.0f;
            #pragma unroll
            for (int j = 0; j < 4; j++)
                s += __expf(acc[i][j][r] + sh[j]);
            // reduce across the 16 n-lanes (lane bits 0..3) — rows identical there
            s += __shfl_xor(s, 1);
            s += __shfl_xor(s, 2);
            s += __shfl_xor(s, 4);
            s += __shfl_xor(s, 8);
            if (col == 0) {
                int mrow = m0 + wm + i * 16 + quad * 4 + r;
                atomicAdd(&rowsum[mrow], s);   // 4096 distinct addresses, ~20 contenders each — fine
            }
        }
    }
}

// ---------------------------------------------------------------- per-row true logit + per-row loss (NO global atomic)
__global__ __launch_bounds__(256) void rowloss_kernel(const float* __restrict__ x,
                                                      const float* __restrict__ w,
                                                      const float* __restrict__ b,
                                                      const int* __restrict__ labels,
                                                      const float* __restrict__ rowsum,
                                                      float* __restrict__ rowloss) {
    __shared__ float red[4];
    const int m = blockIdx.x;
    const int t = threadIdx.x;
    const int lbl = labels[m];
    const float* xr = x + (size_t)m * DIM;
    const float* wc = w + lbl;

    float p = 0.0f;
    #pragma unroll
    for (int d = t; d < DIM; d += 256)
        p += xr[d] * wc[(size_t)d * NUM_CLASSES];

    #pragma unroll
    for (int off = 32; off > 0; off >>= 1)
        p += __shfl_xor(p, off);
    if ((t & 63) == 0) red[t >> 6] = p;
    __syncthreads();
    if (t == 0) {
        float tl = red[0] + red[1] + red[2] + red[3] + b[lbl] - log_expected_count(lbl);
        float total = rowsum[m] + __expf(tl);
        rowloss[m] = logf(total) - tl;
    }
}

// ---------------------------------------------------------------- final mean over 4096 row losses (1 block)
__global__ __launch_bounds__(256) void reduce_kernel(const float* __restrict__ rowloss,
                                                     float* __restrict__ out) {
    __shared__ float red[4];
    const int t = threadIdx.x;
    float s = 0.0f;
    #pragma unroll
    for (int i = t; i < BATCH; i += 256)
        s += rowloss[i];
    #pragma unroll
    for (int off = 32; off > 0; off >>= 1)
        s += __shfl_xor(s, off);
    if ((t & 63) == 0) red[t >> 6] = s;
    __syncthreads();
    if (t == 0)
        out[0] = (red[0] + red[1] + red[2] + red[3]) * (1.0f / (float)BATCH);
}

// ---------------------------------------------------------------- launch
extern "C" void kernel_launch(void* const* d_in, const int* in_sizes, int n_in,
                              void* d_out, int out_size, void* d_ws, size_t ws_size,
                              hipStream_t stream) {
    const float* x       = (const float*)d_in[0];
    const float* w       = (const float*)d_in[1];
    const float* b       = (const float*)d_in[2];
    const int*   labels  = (const int*)d_in[3];
    const int*   sampled = (const int*)d_in[4];
    float* out = (float*)d_out;

    char* ws = (char*)d_ws;
    __hip_bfloat16* A  = (__hip_bfloat16*)(ws);                            // 8 MB
    __hip_bfloat16* BT = (__hip_bfloat16*)(ws + (size_t)8  * 1024 * 1024); // 10 MB
    float* shift   = (float*)(ws + (size_t)18 * 1024 * 1024);              // 20 KB
    float* rowsum  = (float*)(ws + (size_t)18 * 1024 * 1024 + 64 * 1024);  // 16 KB
    float* rowloss = (float*)(ws + (size_t)18 * 1024 * 1024 + 128 * 1024); // 16 KB

    hipLaunchKernelGGL(init_kernel, dim3(16), dim3(256), 0, stream, rowsum);
    hipLaunchKernelGGL(convert_x_kernel, dim3((BATCH * DIM / 4) / 256), dim3(256), 0, stream, x, A);
    hipLaunchKernelGGL(gather_b_kernel, dim3(NPAD / 256, DIM / 16), dim3(256), 0, stream,
                       w, b, sampled, BT, shift);
    hipLaunchKernelGGL(gemm_kernel, dim3(BATCH / BM, NPAD / BN), dim3(256), 0, stream,
                       A, BT, shift, rowsum);
    hipLaunchKernelGGL(rowloss_kernel, dim3(BATCH), dim3(256), 0, stream,
                       x, w, b, labels, rowsum, rowloss);
    hipLaunchKernelGGL(reduce_kernel, dim3(1), dim3(256), 0, stream, rowloss, out);
}